// Round 6
// baseline (130.974 us; speedup 1.0000x reference)
//
#include <hip/hip_runtime.h>

#define KK 4
#define BATCH 32768
#define NN 10
#define GPW 12           // graphs per wave: 3 b's x 4 k's; 5 lanes/graph, 2 nodes/lane
#define SLAB 132         // dwords per graph slab; 132 % 32 = 4 -> <=2-way bank phases
#define NTHREADS 256     // 4 fully independent waves (no cross-wave sync at all)

static constexpr size_t OFF_AIK = (size_t)KK * BATCH * NN * NN;           // 13107200
static constexpr size_t OFF_TJ  = OFF_AIK + (size_t)KK * BATCH * NN;      // 14417920
static constexpr size_t OFF_R   = OFF_TJ  + (size_t)KK * BATCH * NN;      // 15728640
static constexpr size_t OFF_RT  = OFF_R   + (size_t)KK * BATCH * NN * NN; // 28835840

// slab layout (dwords):
//   [0..90)    staged edge weights (phase 1)
//   [0..100)   wt transpose (phase 2; over dead ew)
//   [0..34)    L0 h rows [f*12 + n]   (f=0..2)
//   [0..94)    L1/y2 rows [fo*12 + n] (fo=0..7)
//   [0..118)   ky rows [m*12 + n]     (m=0..9)
//   [120..130) dinv (early) then t_k logits (head phase)
#define WSYNC() do { asm volatile("" ::: "memory"); \
                     __builtin_amdgcn_wave_barrier(); \
                     asm volatile("" ::: "memory"); } while (0)

__device__ __forceinline__ float rcpf(float x) {
#if __has_builtin(__builtin_amdgcn_rcpf)
    return __builtin_amdgcn_rcpf(x);
#else
    return 1.f / x;
#endif
}
__device__ __forceinline__ float fexp2(float x) {
#if __has_builtin(__builtin_amdgcn_exp2f)
    return __builtin_amdgcn_exp2f(x);
#else
    return exp2f(x);
#endif
}

// ---- packed fp32 VOP3P helpers (add/mul/fma only on gfx950). Bit-exact fp32. ----
static __device__ __forceinline__ float2 pk_mul2(float2 a, float2 b) {
    float2 d; asm("v_pk_mul_f32 %0, %1, %2" : "=v"(d) : "v"(a), "v"(b)); return d; }
static __device__ __forceinline__ float2 pk_fma2(float2 a, float2 b, float2 c) {
    float2 d; asm("v_pk_fma_f32 %0, %1, %2, %3" : "=v"(d) : "v"(a), "v"(b), "v"(c)); return d; }
// src0 half broadcast (VGPR pairs): result = src0.lo(/hi) * src1(pair) + c
static __device__ __forceinline__ float2 pk_fma_blo(float2 a, float2 b, float2 c) {
    float2 d; asm("v_pk_fma_f32 %0, %1, %2, %3 op_sel_hi:[0,1,1]"
                  : "=v"(d) : "v"(a), "v"(b), "v"(c)); return d; }
static __device__ __forceinline__ float2 pk_fma_bhi(float2 a, float2 b, float2 c) {
    float2 d; asm("v_pk_fma_f32 %0, %1, %2, %3 op_sel:[1,0,0] op_sel_hi:[1,1,1]"
                  : "=v"(d) : "v"(a), "v"(b), "v"(c)); return d; }
// src1 half broadcast (SGPR pair scalar weight): result = src0(pair) * s.lo(/hi) + c
static __device__ __forceinline__ float2 pk_fma_slo(float2 a, float2 bs, float2 c) {
    float2 d; asm("v_pk_fma_f32 %0, %1, %2, %3 op_sel:[0,0,0] op_sel_hi:[1,0,1]"
                  : "=v"(d) : "v"(a), "s"(bs), "v"(c)); return d; }
static __device__ __forceinline__ float2 pk_fma_shi(float2 a, float2 bs, float2 c) {
    float2 d; asm("v_pk_fma_f32 %0, %1, %2, %3 op_sel:[0,1,0] op_sel_hi:[1,1,1]"
                  : "=v"(d) : "v"(a), "s"(bs), "v"(c)); return d; }
static __device__ __forceinline__ float2 pk_mul_slo(float2 a, float2 bs) {
    float2 d; asm("v_pk_mul_f32 %0, %1, %2 op_sel:[0,0] op_sel_hi:[1,0]"
                  : "=v"(d) : "v"(a), "s"(bs)); return d; }
static __device__ __forceinline__ float2 pk_mul_shi(float2 a, float2 bs) {
    float2 d; asm("v_pk_mul_f32 %0, %1, %2 op_sel:[0,1] op_sel_hi:[1,1]"
                  : "=v"(d) : "v"(a), "s"(bs)); return d; }
static __device__ __forceinline__ float2 pk_add_slo(float2 a, float2 bs) {
    float2 d; asm("v_pk_add_f32 %0, %1, %2 op_sel:[0,0] op_sel_hi:[1,0]"
                  : "=v"(d) : "v"(a), "s"(bs)); return d; }
static __device__ __forceinline__ float2 pk_add_shi(float2 a, float2 bs) {
    float2 d; asm("v_pk_add_f32 %0, %1, %2 op_sel:[0,1] op_sel_hi:[1,1]"
                  : "=v"(d) : "v"(a), "s"(bs)); return d; }
static __device__ __forceinline__ float2 el_max2(float2 a, float2 b) {
    return make_float2(fmaxf(a.x, b.x), fmaxf(a.y, b.y)); }
static __device__ __forceinline__ float2 leaky2(float2 v) {
    return make_float2(fmaxf(v.x, 0.f) + 0.01f * fminf(v.x, 0.f),
                       fmaxf(v.y, 0.f) + 0.01f * fminf(v.y, 0.f)); }

__global__ __launch_bounds__(NTHREADS, 4)
void gnn_fused(const float* __restrict__ xin,
               const float* __restrict__ ew,
               const float* __restrict__ eigen,
               const float* __restrict__ a0p,
               const float* __restrict__ W0p,
               const float* __restrict__ b0p,
               const float* __restrict__ W1p,
               const float* __restrict__ b1p,
               const float* __restrict__ bpp,
               const float* __restrict__ cpp,
               const float* __restrict__ wwp,
               float* __restrict__ out)
{
    __shared__ __align__(16) float sm[KK * GPW * SLAB];   // 25,344 B

    const float LOG2E = 1.4426950408889634f;

    const int t  = threadIdx.x;
    const int l  = t & 63;
    const int w  = t >> 6;
    int gg = l / 5;                    // graph slot in wave 0..12
    const int t5 = l % 5;
    if (gg > 11) gg = 11;              // lanes 60..63 mirror slot 11 (same writes)
    const int kq = gg / 3;             // k index 0..3
    const int bi = gg - 3 * kq;        // 0..2
    const int n0 = 2 * t5;             // this lane's nodes: n0, n0+1
    const int bW0 = blockIdx.x * GPW + 3 * w;    // this wave's first b
    const int bb  = bW0 + bi;
    const bool valid = (bb < BATCH);
    const int bbc = valid ? bb : (BATCH - 1);
    const int g   = kq * BATCH + bbc;

    float* slab = sm + (w * GPW + gg) * SLAB;
    float* wreg = sm + w * GPW * SLAB;

    // ---- phase 1: stage 12 graphs' edge weights (3 b's x 4 k's), wave-local ----
    {
        int nv = BATCH - bW0; nv = (nv > 3) ? 3 : ((nv < 0) ? 0 : nv);
        const unsigned lim = (unsigned)(nv * 45);
#pragma unroll
        for (int k2 = 0; k2 < 4; ++k2) {
            const float* src = ew + ((size_t)k2 * BATCH + bW0) * 90;
#pragma unroll
            for (int it = 0; it < 3; ++it) {
                unsigned idx = (unsigned)(it * 64 + l);     // float2 index < 135
                if (idx < lim) {
                    float2 v = *(const float2*)(src + 2 * idx);
                    unsigned sg3 = idx / 45u, off = idx - sg3 * 45u;
                    *(float2*)(wreg + (k2 * 3 + sg3) * SLAB + 2 * off) = v;
                }
            }
        }
    }

    // ---- global loads for own 2 nodes ----
    const float* xb = xin + (size_t)g * 30 + 6 * t5;
    const float2 f0 = *(const float2*)(xb);
    const float2 f1 = *(const float2*)(xb + 2);
    const float2 f2 = *(const float2*)(xb + 4);
    // node n0: (f0.x, f0.y, f1.x); node n1: (f1.y, f2.x, f2.y)
    const float2 x2p = make_float2(f1.x, f2.y);   // feature-2 pair (for path_mod)
    const float eig = eigen[g];
    const float a0v = a0p[0];

    WSYNC();

    // ---- own outgoing rows (contiguous 18 floats) ----
    float r[18];
    {
        const float* rp = slab + 18 * t5;
#pragma unroll
        for (int i = 0; i < 9; ++i) {
            float2 v = *(const float2*)(rp + 2 * i);
            r[2*i] = v.x; r[2*i+1] = v.y;
        }
    }
    float wA[10], wB[10];     // wout for nodes n0, n1
    {
        const int n1 = n0 + 1;
#pragma unroll
        for (int j = 0; j < 10; ++j) {
            wA[j] = (j == n0) ? 0.f : ((j < n0) ? r[j] : r[j-1]);
            wB[j] = (j == n1) ? 0.f : ((j < n1) ? r[9+j] : r[9+j-1]);
        }
    }

    // ---- R rows (2 rows = 20 contiguous floats, float4 stores) ----
    if (valid) {
        float* pr = out + OFF_R + (size_t)g * 100 + n0 * 10;
        *(float4*)(pr +  0) = make_float4(wA[0]*eig, wA[1]*eig, wA[2]*eig, wA[3]*eig);
        *(float4*)(pr +  4) = make_float4(wA[4]*eig, wA[5]*eig, wA[6]*eig, wA[7]*eig);
        *(float4*)(pr +  8) = make_float4(wA[8]*eig, wA[9]*eig, wB[0]*eig, wB[1]*eig);
        *(float4*)(pr + 12) = make_float4(wB[2]*eig, wB[3]*eig, wB[4]*eig, wB[5]*eig);
        *(float4*)(pr + 16) = make_float4(wB[6]*eig, wB[7]*eig, wB[8]*eig, wB[9]*eig);
    }

    WSYNC();   // all ew reads done; transpose region reusable
    // ---- transpose: wt[j][(n0,n1)] = (w(n0->j), w(n1->j)) ----
#pragma unroll
    for (int j = 0; j < 10; ++j)
        *(float2*)(slab + j * 10 + n0) = make_float2(wA[j], wB[j]);
    WSYNC();
    // ---- incoming rows = wt[n0][:], wt[n1][:] : 20 contiguous floats ----
    float inA[10], inB[10];
    {
        const float* rp = slab + n0 * 10;
#pragma unroll
        for (int i = 0; i < 5; ++i) {
            float2 v = *(const float2*)(rp + 2 * i);
            inA[2*i] = v.x; inA[2*i+1] = v.y;
        }
#pragma unroll
        for (int i = 0; i < 5; ++i) {
            float2 v = *(const float2*)(rp + 10 + 2 * i);
            inB[2*i] = v.x; inB[2*i+1] = v.y;
        }
    }
    float degA = 0.f, degB = 0.f;
#pragma unroll
    for (int m = 0; m < 10; ++m) { degA += inA[m]; degB += inB[m]; }

    // ---- R_t rows ----
    if (valid) {
        float* pt = out + OFF_RT + (size_t)g * 100 + n0 * 10;
        *(float4*)(pt +  0) = make_float4(inA[0]*eig, inA[1]*eig, inA[2]*eig, inA[3]*eig);
        *(float4*)(pt +  4) = make_float4(inA[4]*eig, inA[5]*eig, inA[6]*eig, inA[7]*eig);
        *(float4*)(pt +  8) = make_float4(inA[8]*eig, inA[9]*eig, inB[0]*eig, inB[1]*eig);
        *(float4*)(pt + 12) = make_float4(inB[2]*eig, inB[3]*eig, inB[4]*eig, inB[5]*eig);
        *(float4*)(pt + 16) = make_float4(inB[6]*eig, inB[7]*eig, inB[8]*eig, inB[9]*eig);
    }

    // ---- dinv exchange ----
    const float dvA = (degA > 0.f) ? __frsqrt_rn(degA) : 0.f;
    const float dvB = (degB > 0.f) ? __frsqrt_rn(degB) : 0.f;
    *(float2*)(slab + 120 + n0) = make_float2(dvA, dvB);
    WSYNC();
    float2 arow2[10];   // (arow[n0][m], arow[n1][m])
    {
        float dinv[10];
#pragma unroll
        for (int i = 0; i < 5; ++i) {
            float2 v = *(const float2*)(slab + 120 + 2 * i);
            dinv[2*i] = v.x; dinv[2*i+1] = v.y;
        }
#pragma unroll
        for (int m = 0; m < 10; ++m)
            arow2[m] = make_float2(dinv[m] * inA[m] * dvA, dinv[m] * inB[m] * dvB);
    }

    // ================= TAGConv layer 0: 3 -> 16, packed over nodes =================
    float2 h2[3];
    h2[0] = make_float2(f0.x, f1.y);
    h2[1] = make_float2(f0.y, f2.x);
    h2[2] = x2p;
    float2 acc0p[16];
#pragma unroll
    for (int q = 0; q < 8; ++q) {
        const float2 w0 = *(const float2*)(W0p +  0 + 2*q);
        const float2 w1 = *(const float2*)(W0p + 16 + 2*q);
        const float2 w2 = *(const float2*)(W0p + 32 + 2*q);
        acc0p[2*q]   = pk_mul_slo(h2[0], w0);
        acc0p[2*q]   = pk_fma_slo(h2[1], w1, acc0p[2*q]);
        acc0p[2*q]   = pk_fma_slo(h2[2], w2, acc0p[2*q]);
        acc0p[2*q+1] = pk_mul_shi(h2[0], w0);
        acc0p[2*q+1] = pk_fma_shi(h2[1], w1, acc0p[2*q+1]);
        acc0p[2*q+1] = pk_fma_shi(h2[2], w2, acc0p[2*q+1]);
    }
#pragma unroll
    for (int hop = 1; hop <= 3; ++hop) {
#pragma unroll
        for (int f = 0; f < 3; ++f)
            *(float2*)(slab + f * 12 + n0) = h2[f];
        WSYNC();
        float2 nh[3];
#pragma unroll
        for (int f = 0; f < 3; ++f) {
            const float4 q0 = *(const float4*)(slab + f * 12);
            const float4 q1 = *(const float4*)(slab + f * 12 + 4);
            const float2 q2 = *(const float2*)(slab + f * 12 + 8);
            float2 acc = pk_mul2(make_float2(arow2[0].x * q0.x, arow2[0].y * q0.x),
                                 make_float2(1.f, 1.f));   // placeholder avoided below
            acc = make_float2(0.f, 0.f);
            acc = pk_fma_blo(make_float2(q0.x, q0.y), arow2[0], acc);
            acc = pk_fma_bhi(make_float2(q0.x, q0.y), arow2[1], acc);
            acc = pk_fma_blo(make_float2(q0.z, q0.w), arow2[2], acc);
            acc = pk_fma_bhi(make_float2(q0.z, q0.w), arow2[3], acc);
            acc = pk_fma_blo(make_float2(q1.x, q1.y), arow2[4], acc);
            acc = pk_fma_bhi(make_float2(q1.x, q1.y), arow2[5], acc);
            acc = pk_fma_blo(make_float2(q1.z, q1.w), arow2[6], acc);
            acc = pk_fma_bhi(make_float2(q1.z, q1.w), arow2[7], acc);
            acc = pk_fma_blo(q2, arow2[8], acc);
            acc = pk_fma_bhi(q2, arow2[9], acc);
            nh[f] = acc;
        }
        WSYNC();
#pragma unroll
        for (int q = 0; q < 8; ++q) {
            const float2 w0 = *(const float2*)(W0p + hop*48 +  0 + 2*q);
            const float2 w1 = *(const float2*)(W0p + hop*48 + 16 + 2*q);
            const float2 w2 = *(const float2*)(W0p + hop*48 + 32 + 2*q);
            acc0p[2*q]   = pk_fma_slo(nh[0], w0, acc0p[2*q]);
            acc0p[2*q]   = pk_fma_slo(nh[1], w1, acc0p[2*q]);
            acc0p[2*q]   = pk_fma_slo(nh[2], w2, acc0p[2*q]);
            acc0p[2*q+1] = pk_fma_shi(nh[0], w0, acc0p[2*q+1]);
            acc0p[2*q+1] = pk_fma_shi(nh[1], w1, acc0p[2*q+1]);
            acc0p[2*q+1] = pk_fma_shi(nh[2], w2, acc0p[2*q+1]);
        }
        h2[0] = nh[0]; h2[1] = nh[1]; h2[2] = nh[2];
    }
    float2 y1p[16];
#pragma unroll
    for (int q = 0; q < 8; ++q) {
        const float2 b2 = *(const float2*)(b0p + 2*q);
        y1p[2*q]   = leaky2(pk_add_slo(acc0p[2*q],   b2));
        y1p[2*q+1] = leaky2(pk_add_shi(acc0p[2*q+1], b2));
    }

    // ===== TAGConv layer 1: 16 -> 8, Horner, packed over nodes =====
    float2 cur2[8];
#pragma unroll
    for (int q = 0; q < 4; ++q) {
        {
            const float2 wp = *(const float2*)(W1p + 384 + 0*8 + 2*q);
            cur2[2*q]   = pk_mul_slo(y1p[0], wp);
            cur2[2*q+1] = pk_mul_shi(y1p[0], wp);
        }
#pragma unroll
        for (int fi = 1; fi < 16; ++fi) {
            const float2 wp = *(const float2*)(W1p + 384 + fi*8 + 2*q);
            cur2[2*q]   = pk_fma_slo(y1p[fi], wp, cur2[2*q]);
            cur2[2*q+1] = pk_fma_shi(y1p[fi], wp, cur2[2*q+1]);
        }
    }
#pragma unroll
    for (int kh = 2; kh >= 0; --kh) {
#pragma unroll
        for (int fo = 0; fo < 8; ++fo)
            *(float2*)(slab + fo * 12 + n0) = cur2[fo];
        WSYNC();
        float2 ag[8];
#pragma unroll
        for (int fo = 0; fo < 8; ++fo) {
            const float4 q0 = *(const float4*)(slab + fo * 12);
            const float4 q1 = *(const float4*)(slab + fo * 12 + 4);
            const float2 q2 = *(const float2*)(slab + fo * 12 + 8);
            float2 acc = make_float2(0.f, 0.f);
            acc = pk_fma_blo(make_float2(q0.x, q0.y), arow2[0], acc);
            acc = pk_fma_bhi(make_float2(q0.x, q0.y), arow2[1], acc);
            acc = pk_fma_blo(make_float2(q0.z, q0.w), arow2[2], acc);
            acc = pk_fma_bhi(make_float2(q0.z, q0.w), arow2[3], acc);
            acc = pk_fma_blo(make_float2(q1.x, q1.y), arow2[4], acc);
            acc = pk_fma_bhi(make_float2(q1.x, q1.y), arow2[5], acc);
            acc = pk_fma_blo(make_float2(q1.z, q1.w), arow2[6], acc);
            acc = pk_fma_bhi(make_float2(q1.z, q1.w), arow2[7], acc);
            acc = pk_fma_blo(q2, arow2[8], acc);
            acc = pk_fma_bhi(q2, arow2[9], acc);
            ag[fo] = acc;
        }
        WSYNC();
#pragma unroll
        for (int q = 0; q < 4; ++q) {
            cur2[2*q] = ag[2*q]; cur2[2*q+1] = ag[2*q+1];
#pragma unroll
            for (int fi = 0; fi < 16; ++fi) {
                const float2 wp = *(const float2*)(W1p + kh*128 + fi*8 + 2*q);
                cur2[2*q]   = pk_fma_slo(y1p[fi], wp, cur2[2*q]);
                cur2[2*q+1] = pk_fma_shi(y1p[fi], wp, cur2[2*q+1]);
            }
        }
    }
    float2 y2p[8];
#pragma unroll
    for (int q = 0; q < 4; ++q) {
        const float2 b2 = *(const float2*)(b1p + 2*q);
        y2p[2*q]   = leaky2(pk_add_slo(cur2[2*q],   b2));
        y2p[2*q+1] = leaky2(pk_add_shi(cur2[2*q+1], b2));
    }

    // ================= heads =================
#pragma unroll
    for (int d = 0; d < 8; ++d)
        *(float2*)(slab + d * 12 + n0) = y2p[d];

    float2 accA = make_float2(0.f, 0.f), accT = make_float2(0.f, 0.f);
#pragma unroll
    for (int q = 0; q < 4; ++q) {
        const float2 bp2 = *(const float2*)(bpp + 2*q);
        const float2 cp2 = *(const float2*)(cpp + 2*q);
        accA = pk_fma_slo(y2p[2*q], bp2, accA);
        accA = pk_fma_shi(y2p[2*q+1], bp2, accA);
        accT = pk_fma_slo(y2p[2*q], cp2, accT);
        accT = pk_fma_shi(y2p[2*q+1], cp2, accT);
    }
    if (valid)
        *(float2*)(out + OFF_AIK + (size_t)g * 10 + n0) =
            make_float2(a0v + fmaxf(accA.x, 0.f), a0v + fmaxf(accA.y, 0.f));

    float tkx = accT.x * (1.f - fmaxf(x2p.x, 0.f));
    float tky = accT.y * (1.f - fmaxf(x2p.y, 0.f));
    if (tkx == 0.f) tkx = -1e10f;
    if (tky == 0.f) tky = -1e10f;
    const float2 tks = make_float2(tkx * LOG2E, tky * LOG2E);

    float2 yw2[8];   // (yw[n0][d], yw[n1][d]) * LOG2E
    {
        const float2 lg2 = make_float2(LOG2E, LOG2E);
#pragma unroll
        for (int d = 0; d < 8; ++d) {
            float2 a = make_float2(0.f, 0.f);
#pragma unroll
            for (int e2 = 0; e2 < 4; ++e2) {
                const float2 wp = *(const float2*)(wwp + d*8 + 2*e2);
                a = pk_fma_slo(y2p[2*e2],   wp, a);
                a = pk_fma_shi(y2p[2*e2+1], wp, a);
            }
            yw2[d] = pk_mul2(a, lg2);
        }
    }
    WSYNC();   // y2 rows visible
    float2 ky2[10];
#pragma unroll
    for (int m = 0; m < 10; ++m) ky2[m] = make_float2(0.f, 0.f);
#pragma unroll
    for (int d = 0; d < 8; ++d) {
        const float4 q0 = *(const float4*)(slab + d * 12);
        const float4 q1 = *(const float4*)(slab + d * 12 + 4);
        const float2 q2 = *(const float2*)(slab + d * 12 + 8);
        ky2[0] = pk_fma_blo(make_float2(q0.x, q0.y), yw2[d], ky2[0]);
        ky2[1] = pk_fma_bhi(make_float2(q0.x, q0.y), yw2[d], ky2[1]);
        ky2[2] = pk_fma_blo(make_float2(q0.z, q0.w), yw2[d], ky2[2]);
        ky2[3] = pk_fma_bhi(make_float2(q0.z, q0.w), yw2[d], ky2[3]);
        ky2[4] = pk_fma_blo(make_float2(q1.x, q1.y), yw2[d], ky2[4]);
        ky2[5] = pk_fma_bhi(make_float2(q1.x, q1.y), yw2[d], ky2[5]);
        ky2[6] = pk_fma_blo(make_float2(q1.z, q1.w), yw2[d], ky2[6]);
        ky2[7] = pk_fma_bhi(make_float2(q1.z, q1.w), yw2[d], ky2[7]);
        ky2[8] = pk_fma_blo(q2, yw2[d], ky2[8]);
        ky2[9] = pk_fma_bhi(q2, yw2[d], ky2[9]);
    }
    WSYNC();   // all y2 reads done; region reusable for ky
#pragma unroll
    for (int m = 0; m < 10; ++m)
        *(float2*)(slab + m * 12 + n0) = ky2[m];
    *(float2*)(slab + 120 + n0) = tks;
    WSYNC();   // wave-local "barrier": all 4 k's of this wave are in this wave

    // ---- t softmax over K (exp2 domain) ----
    {
        const int base = w * GPW;
        const float2 v0 = *(const float2*)(sm + (base + 0*3 + bi)*SLAB + 120 + n0);
        const float2 v1 = *(const float2*)(sm + (base + 1*3 + bi)*SLAB + 120 + n0);
        const float2 v2 = *(const float2*)(sm + (base + 2*3 + bi)*SLAB + 120 + n0);
        const float2 v3 = *(const float2*)(sm + (base + 3*3 + bi)*SLAB + 120 + n0);
        const float2 mx = el_max2(el_max2(v0, v1), el_max2(v2, v3));
        const float dl = fexp2(v0.x-mx.x) + fexp2(v1.x-mx.x) + fexp2(v2.x-mx.x) + fexp2(v3.x-mx.x);
        const float dh = fexp2(v0.y-mx.y) + fexp2(v1.y-mx.y) + fexp2(v2.y-mx.y) + fexp2(v3.y-mx.y);
        if (valid)
            *(float2*)(out + OFF_TJ + (size_t)g * 10 + n0) =
                make_float2(fexp2(tks.x - mx.x) * rcpf(dl),
                            fexp2(tks.y - mx.y) * rcpf(dh));
    }
    // ---- k_ij softmax over K (exp2 domain) ----
    {
        const int base = w * GPW;
        const float* s0 = sm + (base + 0*3 + bi)*SLAB;
        const float* s1 = sm + (base + 1*3 + bi)*SLAB;
        const float* s2 = sm + (base + 2*3 + bi)*SLAB;
        const float* s3 = sm + (base + 3*3 + bi)*SLAB;
        float ox[10], oy[10];
#pragma unroll
        for (int m = 0; m < 10; ++m) {
            const float2 a = *(const float2*)(s0 + m*12 + n0);
            const float2 b = *(const float2*)(s1 + m*12 + n0);
            const float2 c = *(const float2*)(s2 + m*12 + n0);
            const float2 d = *(const float2*)(s3 + m*12 + n0);
            const float2 mx = el_max2(el_max2(a, b), el_max2(c, d));
            const float dl = fexp2(a.x-mx.x) + fexp2(b.x-mx.x) + fexp2(c.x-mx.x) + fexp2(d.x-mx.x);
            const float dh = fexp2(a.y-mx.y) + fexp2(b.y-mx.y) + fexp2(c.y-mx.y) + fexp2(d.y-mx.y);
            ox[m] = fexp2(ky2[m].x - mx.x) * rcpf(dl);
            oy[m] = fexp2(ky2[m].y - mx.y) * rcpf(dh);
        }
        if (valid) {
            float* po = out + (size_t)g * 100 + n0 * 10;
            *(float4*)(po +  0) = make_float4(ox[0], ox[1], ox[2], ox[3]);
            *(float4*)(po +  4) = make_float4(ox[4], ox[5], ox[6], ox[7]);
            *(float4*)(po +  8) = make_float4(ox[8], ox[9], oy[0], oy[1]);
            *(float4*)(po + 12) = make_float4(oy[2], oy[3], oy[4], oy[5]);
            *(float4*)(po + 16) = make_float4(oy[6], oy[7], oy[8], oy[9]);
        }
    }
}

extern "C" void kernel_launch(void* const* d_in, const int* in_sizes, int n_in,
                              void* d_out, int out_size, void* d_ws, size_t ws_size,
                              hipStream_t stream) {
    const float* x   = (const float*)d_in[0];
    // d_in[1] = edge_index: deterministic pattern, never read
    const float* ew  = (const float*)d_in[2];
    const float* eig = (const float*)d_in[6];
    const float* a0  = (const float*)d_in[7];
    const float* W0  = (const float*)d_in[8];
    const float* b0  = (const float*)d_in[9];
    const float* W1  = (const float*)d_in[10];
    const float* b1  = (const float*)d_in[11];
    const float* bpw = (const float*)d_in[12];
    const float* cpw = (const float*)d_in[13];
    const float* www = (const float*)d_in[14];
    float* out = (float*)d_out;

    const int grid = (BATCH + GPW - 1) / GPW;   // 2731
    gnn_fused<<<dim3(grid), dim3(NTHREADS), 0, stream>>>(
        x, ew, eig, a0, W0, b0, W1, b1, bpw, cpw, www, out);
}

// Round 7
// 75.970 us; speedup vs baseline: 1.7240x; 1.7240x over previous
//
#include <hip/hip_runtime.h>

#define KK 4
#define BATCH 32768
#define NN 10
#define GPW 6            // graphs per wave (10 lanes each, 60 of 64 lanes)
#define SLAB 132         // dwords per graph slab; 132 % 32 = 4 -> slab banks spread 4*s
#define NTHREADS 256     // 4 waves; wave w == k index

static constexpr size_t OFF_AIK = (size_t)KK * BATCH * NN * NN;           // 13107200
static constexpr size_t OFF_TJ  = OFF_AIK + (size_t)KK * BATCH * NN;      // 14417920
static constexpr size_t OFF_R   = OFF_TJ  + (size_t)KK * BATCH * NN;      // 15728640
static constexpr size_t OFF_RT  = OFF_R   + (size_t)KK * BATCH * NN * NN; // 28835840

// slab layout (dwords):
//   [0..100)   wt transpose (early), then h/y2 exchange rows at n*12 [0..120),
//              then ky rows at n*10 [0..100) (stride 10 -> 16 bank classes on k_ij reads)
//   [120..130) dinv (early) then t_k logits (head phase)
#define WSYNC() do { asm volatile("" ::: "memory"); \
                     __builtin_amdgcn_wave_barrier(); \
                     asm volatile("" ::: "memory"); } while (0)

__device__ __forceinline__ float rcpf(float x) {
#if __has_builtin(__builtin_amdgcn_rcpf)
    return __builtin_amdgcn_rcpf(x);
#else
    return 1.f / x;
#endif
}
__device__ __forceinline__ float fexp2(float x) {
#if __has_builtin(__builtin_amdgcn_exp2f)
    return __builtin_amdgcn_exp2f(x);
#else
    return exp2f(x);
#endif
}

// ---- packed fp32 helpers (VOP3P; add/mul/fma only on gfx950). Bit-exact IEEE fp32. ----
static __device__ __forceinline__ float2 pk_mul2(float2 a, float2 b) {
    float2 d; asm("v_pk_mul_f32 %0, %1, %2" : "=v"(d) : "v"(a), "v"(b)); return d; }
static __device__ __forceinline__ float2 pk_fma2(float2 a, float2 b, float2 c) {
    float2 d; asm("v_pk_fma_f32 %0, %1, %2, %3" : "=v"(d) : "v"(a), "v"(b), "v"(c)); return d; }
// broadcast src0.lo (or .hi) across both result halves
static __device__ __forceinline__ float2 pk_fma_blo(float2 a, float2 b, float2 c) {
    float2 d; asm("v_pk_fma_f32 %0, %1, %2, %3 op_sel_hi:[0,1,1]"
                  : "=v"(d) : "v"(a), "v"(b), "v"(c)); return d; }
static __device__ __forceinline__ float2 pk_fma_bhi(float2 a, float2 b, float2 c) {
    float2 d; asm("v_pk_fma_f32 %0, %1, %2, %3 op_sel:[1,0,0] op_sel_hi:[1,1,1]"
                  : "=v"(d) : "v"(a), "v"(b), "v"(c)); return d; }
// same, with wave-uniform weight pair held in SGPRs (src1)
static __device__ __forceinline__ float2 pk_fma_blo_s(float2 a, float2 bs, float2 c) {
    float2 d; asm("v_pk_fma_f32 %0, %1, %2, %3 op_sel_hi:[0,1,1]"
                  : "=v"(d) : "v"(a), "s"(bs), "v"(c)); return d; }
static __device__ __forceinline__ float2 pk_fma_bhi_s(float2 a, float2 bs, float2 c) {
    float2 d; asm("v_pk_fma_f32 %0, %1, %2, %3 op_sel:[1,0,0] op_sel_hi:[1,1,1]"
                  : "=v"(d) : "v"(a), "s"(bs), "v"(c)); return d; }
static __device__ __forceinline__ float2 pk_mul_blo_s(float2 a, float2 bs) {
    float2 d; asm("v_pk_mul_f32 %0, %1, %2 op_sel_hi:[0,1]"
                  : "=v"(d) : "v"(a), "s"(bs)); return d; }
static __device__ __forceinline__ float2 pk_fma_vs(float2 a, float2 bs, float2 c) {
    float2 d; asm("v_pk_fma_f32 %0, %1, %2, %3" : "=v"(d) : "v"(a), "s"(bs), "v"(c)); return d; }
static __device__ __forceinline__ float2 pk_add_vs(float2 a, float2 bs) {
    float2 d; asm("v_pk_add_f32 %0, %1, %2" : "=v"(d) : "v"(a), "s"(bs)); return d; }
static __device__ __forceinline__ float2 el_max2(float2 a, float2 b) {
    return make_float2(fmaxf(a.x, b.x), fmaxf(a.y, b.y)); }
static __device__ __forceinline__ float2 leaky2(float2 v) {
    return make_float2(fmaxf(v.x, 0.f) + 0.01f * fminf(v.x, 0.f),
                       fmaxf(v.y, 0.f) + 0.01f * fminf(v.y, 0.f)); }

__global__ __launch_bounds__(NTHREADS, 8)
void gnn_fused(const float* __restrict__ xin,
               const float* __restrict__ ew,
               const float* __restrict__ eigen,
               const float* __restrict__ a0p,
               const float* __restrict__ W0p,
               const float* __restrict__ b0p,
               const float* __restrict__ W1p,
               const float* __restrict__ b1p,
               const float* __restrict__ bpp,
               const float* __restrict__ cpp,
               const float* __restrict__ wwp,
               float* __restrict__ out)
{
    __shared__ __align__(16) float sm[KK * GPW * SLAB];   // 12,672 B

    const float LOG2E = 1.4426950408889634f;

    const int t = threadIdx.x;
    const int l = t & 63;
    const int w = t >> 6;             // k index
    int s = l / 10;                   // graph in wave 0..6
    const int n = l % 10;             // node
    const bool dup = (s >= GPW);
    if (dup) s = GPW - 1;
    const int bb  = blockIdx.x * GPW + s;
    const bool valid = (!dup) && (bb < BATCH);
    const int bbc = (bb < BATCH) ? bb : (BATCH - 1);
    const int g   = w * BATCH + bbc;

    float* slab = sm + (w * GPW + s) * SLAB;

    // ---- own outgoing edge-weight row DIRECT from global (no LDS staging) ----
    // edge e = i*9 + r : src i, dst j = (r<i) ? r : r+1; row n = ew[g*90 + n*9 ..+9)
    float rowv[9];
    {
        const float* rp = ew + (size_t)g * 90 + n * 9;
#pragma unroll
        for (int c = 0; c < 9; ++c) rowv[c] = rp[c];
    }
    const size_t node = (size_t)g * NN + n;
    const float x0 = xin[node * 3 + 0];
    const float x1 = xin[node * 3 + 1];
    const float x2 = xin[node * 3 + 2];
    const float eig = eigen[g];
    const float a0v = a0p[0];

    float wout[10];
    wout[0] = (n == 0) ? 0.f : rowv[0];
    wout[9] = (n == 9) ? 0.f : rowv[8];
#pragma unroll
    for (int j = 1; j < 9; ++j)
        wout[j] = (j == n) ? 0.f : ((j < n) ? rowv[j] : rowv[j - 1]);

    // ---- R (row n = outgoing) ----
    if (valid) {
        float* pr = out + OFF_R + (size_t)g * 100 + n * 10;
#pragma unroll
        for (int q = 0; q < 5; ++q)
            ((float2*)pr)[q] = make_float2(wout[2*q] * eig, wout[2*q+1] * eig);
    }

    // ---- transpose through LDS: wt[j][n] = w(n->j) ----
#pragma unroll
    for (int j = 0; j < 10; ++j) slab[j * 10 + n] = wout[j];
    WSYNC();
    // incoming row = wt[n][0..9], contiguous b64 reads
    float2 win2[5];
    {
        const float* rp = slab + n * 10;
#pragma unroll
        for (int q = 0; q < 5; ++q) win2[q] = *(const float2*)(rp + 2 * q);
    }
    const float deg = (win2[0].x + win2[0].y) + (win2[1].x + win2[1].y)
                    + (win2[2].x + win2[2].y) + (win2[3].x + win2[3].y)
                    + (win2[4].x + win2[4].y);

    // ---- R_t (row n = incoming) ----
    if (valid) {
        float* pt = out + OFF_RT + (size_t)g * 100 + n * 10;
#pragma unroll
        for (int q = 0; q < 5; ++q)
            ((float2*)pt)[q] = make_float2(win2[q].x * eig, win2[q].y * eig);
    }

    // ---- dinv exchange ----
    const float dv = (deg > 0.f) ? __frsqrt_rn(deg) : 0.f;
    slab[120 + n] = dv;
    WSYNC();
    float2 dinv2[5];
#pragma unroll
    for (int q = 0; q < 5; ++q) dinv2[q] = *(const float2*)(slab + 120 + 2 * q);
    const float2 dv2 = make_float2(dv, dv);
    float2 arow2[5];
#pragma unroll
    for (int q = 0; q < 5; ++q)
        arow2[q] = pk_mul2(pk_mul2(dinv2[q], win2[q]), dv2);

    // ================= TAGConv layer 0: 3 -> 16, packed =================
    const float2 x01 = make_float2(x0, x1);
    const float2 x2p = make_float2(x2, 0.f);
    float2 acc0p[8];
#pragma unroll
    for (int q = 0; q < 8; ++q) {
        float2 wa = *(const float2*)(W0p + 2*q);
        float2 wb = *(const float2*)(W0p + 16 + 2*q);
        float2 wc = *(const float2*)(W0p + 32 + 2*q);
        acc0p[q] = pk_mul_blo_s(x01, wa);
        acc0p[q] = pk_fma_bhi_s(x01, wb, acc0p[q]);
        acc0p[q] = pk_fma_blo_s(x2p, wc, acc0p[q]);
    }
    {
        float2 hab = x01, hcj = x2p;
#pragma unroll
        for (int hop = 1; hop <= 3; ++hop) {
            *(float4*)(slab + n * 12) = make_float4(hab.x, hab.y, hcj.x, hcj.y);
            WSYNC();
            float2 nab = make_float2(0.f, 0.f), ncj = make_float2(0.f, 0.f);
#pragma unroll
            for (int m = 0; m < 10; ++m) {
                const float4 hm = *(const float4*)(slab + m * 12);
                const float2 hx = make_float2(hm.x, hm.y);
                const float2 hz = make_float2(hm.z, hm.w);
                const float2 am = arow2[m >> 1];
                if ((m & 1) == 0) {
                    nab = pk_fma_blo(am, hx, nab);
                    ncj = pk_fma_blo(am, hz, ncj);
                } else {
                    nab = pk_fma_bhi(am, hx, nab);
                    ncj = pk_fma_bhi(am, hz, ncj);
                }
            }
            WSYNC();
#pragma unroll
            for (int q = 0; q < 8; ++q) {
                float2 wa = *(const float2*)(W0p + hop*48 + 2*q);
                float2 wb = *(const float2*)(W0p + hop*48 + 16 + 2*q);
                float2 wc = *(const float2*)(W0p + hop*48 + 32 + 2*q);
                acc0p[q] = pk_fma_blo_s(nab, wa, acc0p[q]);
                acc0p[q] = pk_fma_bhi_s(nab, wb, acc0p[q]);
                acc0p[q] = pk_fma_blo_s(ncj, wc, acc0p[q]);
            }
            hab = nab; hcj = ncj;
        }
    }
    const float2 zero2 = make_float2(0.f, 0.f);
    float2 y1p[8];
#pragma unroll
    for (int q = 0; q < 8; ++q) {
        float2 b2 = *(const float2*)(b0p + 2*q);
        y1p[q] = leaky2(pk_add_vs(acc0p[q], b2));
    }

    // ===== TAGConv layer 1: 16 -> 8, Horner, packed: out = z0+A(z1+A(z2+A z3)) =====
    float2 cur2[4];
#pragma unroll
    for (int q = 0; q < 4; ++q) {
        float2 w0 = *(const float2*)(W1p + 384 + 2*q);
        cur2[q] = pk_mul_blo_s(y1p[0], w0);
        float2 w1 = *(const float2*)(W1p + 384 + 8 + 2*q);
        cur2[q] = pk_fma_bhi_s(y1p[0], w1, cur2[q]);
#pragma unroll
        for (int p8 = 1; p8 < 8; ++p8) {
            float2 wl = *(const float2*)(W1p + 384 + (2*p8)*8 + 2*q);
            float2 wh = *(const float2*)(W1p + 384 + (2*p8+1)*8 + 2*q);
            cur2[q] = pk_fma_blo_s(y1p[p8], wl, cur2[q]);
            cur2[q] = pk_fma_bhi_s(y1p[p8], wh, cur2[q]);
        }
    }
#pragma unroll
    for (int kh = 2; kh >= 0; --kh) {
        *(float4*)(slab + n * 12)     = make_float4(cur2[0].x, cur2[0].y, cur2[1].x, cur2[1].y);
        *(float4*)(slab + n * 12 + 4) = make_float4(cur2[2].x, cur2[2].y, cur2[3].x, cur2[3].y);
        WSYNC();
        float2 ag[4] = {zero2, zero2, zero2, zero2};
#pragma unroll
        for (int m = 0; m < 10; ++m) {
            const float4 p = *(const float4*)(slab + m * 12);
            const float4 r = *(const float4*)(slab + m * 12 + 4);
            const float2 pa = make_float2(p.x, p.y), pb = make_float2(p.z, p.w);
            const float2 ra = make_float2(r.x, r.y), rb = make_float2(r.z, r.w);
            const float2 am = arow2[m >> 1];
            if ((m & 1) == 0) {
                ag[0] = pk_fma_blo(am, pa, ag[0]);
                ag[1] = pk_fma_blo(am, pb, ag[1]);
                ag[2] = pk_fma_blo(am, ra, ag[2]);
                ag[3] = pk_fma_blo(am, rb, ag[3]);
            } else {
                ag[0] = pk_fma_bhi(am, pa, ag[0]);
                ag[1] = pk_fma_bhi(am, pb, ag[1]);
                ag[2] = pk_fma_bhi(am, ra, ag[2]);
                ag[3] = pk_fma_bhi(am, rb, ag[3]);
            }
        }
        WSYNC();
#pragma unroll
        for (int q = 0; q < 4; ++q) {
            cur2[q] = ag[q];
#pragma unroll
            for (int p8 = 0; p8 < 8; ++p8) {
                float2 wl = *(const float2*)(W1p + kh*128 + (2*p8)*8 + 2*q);
                float2 wh = *(const float2*)(W1p + kh*128 + (2*p8+1)*8 + 2*q);
                cur2[q] = pk_fma_blo_s(y1p[p8], wl, cur2[q]);
                cur2[q] = pk_fma_bhi_s(y1p[p8], wh, cur2[q]);
            }
        }
    }
    float2 y2p[4];
#pragma unroll
    for (int q = 0; q < 4; ++q) {
        float2 b2 = *(const float2*)(b1p + 2*q);
        y2p[q] = leaky2(pk_add_vs(cur2[q], b2));
    }

    // ================= heads =================
    *(float4*)(slab + n * 12)     = make_float4(y2p[0].x, y2p[0].y, y2p[1].x, y2p[1].y);
    *(float4*)(slab + n * 12 + 4) = make_float4(y2p[2].x, y2p[2].y, y2p[3].x, y2p[3].y);

    float2 accA = zero2, accT = zero2;
#pragma unroll
    for (int q = 0; q < 4; ++q) {
        float2 bp2 = *(const float2*)(bpp + 2*q);
        float2 cp2 = *(const float2*)(cpp + 2*q);
        accA = pk_fma_vs(y2p[q], bp2, accA);
        accT = pk_fma_vs(y2p[q], cp2, accT);
    }
    const float ay = accA.x + accA.y;
    const float ty = accT.x + accT.y;
    if (valid)
        out[OFF_AIK + (size_t)g * 10 + n] = a0v + fmaxf(ay, 0.f);

    float tk = ty * (1.f - fmaxf(x2, 0.f));
    if (tk == 0.f) tk = -1e10f;
    const float tks = tk * LOG2E;     // exp2-scaled logit

    float2 yw2[4];
#pragma unroll
    for (int qd = 0; qd < 4; ++qd) {
        float2 aA = zero2, aB = zero2;
#pragma unroll
        for (int q = 0; q < 4; ++q) {
            float2 wA = *(const float2*)(wwp + (2*qd)*8 + 2*q);
            float2 wB = *(const float2*)(wwp + (2*qd+1)*8 + 2*q);
            aA = pk_fma_vs(y2p[q], wA, aA);
            aB = pk_fma_vs(y2p[q], wB, aB);
        }
        yw2[qd] = make_float2(aA.x + aA.y, aB.x + aB.y);
    }
    WSYNC();   // y2 rows visible
    float kyr[10];
#pragma unroll
    for (int m = 0; m < 10; ++m) {
        const float4 p = *(const float4*)(slab + m * 12);
        const float4 r = *(const float4*)(slab + m * 12 + 4);
        float2 acc = pk_mul2(yw2[0], make_float2(p.x, p.y));
        acc = pk_fma2(yw2[1], make_float2(p.z, p.w), acc);
        acc = pk_fma2(yw2[2], make_float2(r.x, r.y), acc);
        acc = pk_fma2(yw2[3], make_float2(r.z, r.w), acc);
        kyr[m] = (acc.x + acc.y) * LOG2E;   // exp2-scaled
    }
    WSYNC();   // all y2 reads done; region reusable for ky (stride 10)
#pragma unroll
    for (int q = 0; q < 5; ++q)
        *(float2*)(slab + n * 10 + 2*q) = make_float2(kyr[2*q], kyr[2*q+1]);
    slab[120 + n] = tks;

    __syncthreads();   // the ONE cross-wave barrier

    // ---- t softmax over K (exp2 domain, exp-reuse) ----
    {
        const float tv0 = sm[(0*GPW + s)*SLAB + 120 + n];
        const float tv1 = sm[(1*GPW + s)*SLAB + 120 + n];
        const float tv2 = sm[(2*GPW + s)*SLAB + 120 + n];
        const float tv3 = sm[(3*GPW + s)*SLAB + 120 + n];
        const float mx = fmaxf(fmaxf(tv0, tv1), fmaxf(tv2, tv3));
        const float e0 = fexp2(tv0-mx), e1 = fexp2(tv1-mx);
        const float e2 = fexp2(tv2-mx), e3 = fexp2(tv3-mx);
        const float den = e0 + e1 + e2 + e3;
        const float own = (w == 0) ? e0 : (w == 1) ? e1 : (w == 2) ? e2 : e3;
        if (valid)
            out[OFF_TJ + (size_t)g * 10 + n] = own * rcpf(den);
    }
    // ---- k_ij softmax over K (exp2 domain, exp-reuse) ----
    {
        const float* k0 = sm + (0*GPW + s)*SLAB + n * 10;
        const float* k1 = sm + (1*GPW + s)*SLAB + n * 10;
        const float* k2 = sm + (2*GPW + s)*SLAB + n * 10;
        const float* k3 = sm + (3*GPW + s)*SLAB + n * 10;
        float* po = out + (size_t)g * 100 + n * 10;
#pragma unroll
        for (int q = 0; q < 5; ++q) {
            const float2 a = *(const float2*)(k0 + 2*q);
            const float2 b = *(const float2*)(k1 + 2*q);
            const float2 c = *(const float2*)(k2 + 2*q);
            const float2 d = *(const float2*)(k3 + 2*q);
            const float2 mx2v = el_max2(el_max2(a, b), el_max2(c, d));
            const float eax = fexp2(a.x-mx2v.x), ebx = fexp2(b.x-mx2v.x);
            const float ecx = fexp2(c.x-mx2v.x), edx = fexp2(d.x-mx2v.x);
            const float eay = fexp2(a.y-mx2v.y), eby = fexp2(b.y-mx2v.y);
            const float ecy = fexp2(c.y-mx2v.y), edy = fexp2(d.y-mx2v.y);
            const float dl = eax + ebx + ecx + edx;
            const float dh = eay + eby + ecy + edy;
            const float ox = (w == 0) ? eax : (w == 1) ? ebx : (w == 2) ? ecx : edx;
            const float oy = (w == 0) ? eay : (w == 1) ? eby : (w == 2) ? ecy : edy;
            if (valid)
                ((float2*)po)[q] = make_float2(ox * rcpf(dl), oy * rcpf(dh));
        }
    }
}

extern "C" void kernel_launch(void* const* d_in, const int* in_sizes, int n_in,
                              void* d_out, int out_size, void* d_ws, size_t ws_size,
                              hipStream_t stream) {
    const float* x   = (const float*)d_in[0];
    // d_in[1] = edge_index: deterministic pattern, never read
    const float* ew  = (const float*)d_in[2];
    const float* eig = (const float*)d_in[6];
    const float* a0  = (const float*)d_in[7];
    const float* W0  = (const float*)d_in[8];
    const float* b0  = (const float*)d_in[9];
    const float* W1  = (const float*)d_in[10];
    const float* b1  = (const float*)d_in[11];
    const float* bpw = (const float*)d_in[12];
    const float* cpw = (const float*)d_in[13];
    const float* www = (const float*)d_in[14];
    float* out = (float*)d_out;

    const int grid = (BATCH + GPW - 1) / GPW;   // 5462
    gnn_fused<<<dim3(grid), dim3(NTHREADS), 0, stream>>>(
        x, ew, eig, a0, W0, b0, W1, b1, bpw, cpw, www, out);
}